// Round 4
// baseline (587.998 us; speedup 1.0000x reference)
//
#include <hip/hip_runtime.h>
#include <math.h>

typedef float f4 __attribute__((ext_vector_type(4)));

#define PLANE (4096*4096)

// ---- output offsets (floats), concatenated return order ----
#define OUT_COL 0
#define OUT_ROW 262144
#define OUT_OBJ 524288
#define OUT_CV  524352
#define OUT_VC  34078784
#define OUT_VO  67633216
#define OUT_CO  67641408

// ---- workspace offsets (floats) ----
#define WS_VO_P 0        // [16][64] v->o attention per-block partials
#define WS_CO_P 1024     // [16][64] c->o attention per-block partials
#define WS_OBJ1 2048     // [64]  obj after v->o update
#define WS_RDCV 2112     // [4096] row_hidden . w_cv_row
#define WS_CDCV 6208     // [4096] col_hidden . w_cv_col
#define WS_RDVC 10304    // [4096] row_next . w_vc_row
#define WS_CDVC 14400    // [4096] col_hidden . w_vc_col
#define WS_PART 18496    // [64][4096*64] j-split partials (64 MB)

__device__ __forceinline__ float sigf(float x) {
    return 1.0f / (1.0f + __expf(-x));
}

// ---------------------------------------------------------------------------
// Attention body over 4096 nodes (one 256-thread block handles 256 nodes):
//   a[i] = sigmoid(X[i].wat[0:64] + supp[i].wat[64:66] + obj.wat[66:130] + b)
//   accP[blk][h] = sum_{i in blk} a[i]*X[i,h]   (per-block partial, no atomics)
// Optionally dextra[i] = X[i].wextra (fused row_next . w_vc_row).
__device__ __forceinline__ void attn_body(
    int blk, int t, const float* __restrict__ X, const float* __restrict__ supp,
    const float* __restrict__ obj, const float* __restrict__ wat,
    const float* __restrict__ bat, float* __restrict__ accP,
    const float* __restrict__ wextra, float* __restrict__ dextra,
    float* sA, float* sAcc)
{
    const int i = blk * 256 + t;
    float od = 0.f;
    for (int h = 0; h < 64; ++h) od += obj[h] * wat[66 + h];
    float x = bat[0] + od + supp[i*2] * wat[64] + supp[i*2+1] * wat[65];
    const f4* Xr = (const f4*)(X + i*64);
    f4 xd = 0.f, dd = 0.f;
    #pragma unroll
    for (int q = 0; q < 16; ++q) {
        f4 xv = Xr[q];
        xd += xv * ((const f4*)wat)[q];
        if (wextra) dd += xv * ((const f4*)wextra)[q];
    }
    x += xd.x + xd.y + xd.z + xd.w;
    if (dextra) dextra[i] = dd.x + dd.y + dd.z + dd.w;
    sA[t] = sigf(x);
    if (t < 64) sAcc[t] = 0.f;
    __syncthreads();
    const int w = t >> 6, h = t & 63;
    const int base = blk * 256 + w * 64;
    float partial = 0.f;
    for (int j = 0; j < 64; ++j)
        partial += sA[w*64 + j] * X[(base + j)*64 + h];
    atomicAdd(&sAcc[h], partial);
    __syncthreads();
    if (t < 64) accP[blk*64 + t] = sAcc[t];
}

// ---------------------------------------------------------------------------
// Front kernel: 3072 dot blocks + 16 small-copy blocks + 16 v->o attention blocks.
__global__ __launch_bounds__(256) void k_front(
    const float* __restrict__ col_hidden, const float* __restrict__ row_hidden,
    const float* __restrict__ w_cv_col, const float* __restrict__ w_vc_col,
    const float* __restrict__ w_cv_row,
    float* __restrict__ cdcv, float* __restrict__ cdvc, float* __restrict__ rdcv,
    const float* __restrict__ vo_supp, const float* __restrict__ co_supp,
    float* __restrict__ out_vo, float* __restrict__ out_co,
    const float* __restrict__ obj_hidden, const float* __restrict__ w_attn_vo,
    const float* __restrict__ b_attn_vo, float* __restrict__ voP)
{
    __shared__ float sA[256];
    __shared__ float sAcc[64];
    const int t = threadIdx.x;
    if (blockIdx.x < 3072) {
        const int gw = blockIdx.x * 4 + (t >> 6);
        const int lane = t & 63;
        const int which = gw >> 12;       // 0,1,2
        const int row = gw & 4095;
        const float* x; const float* w; float* dst;
        if (which == 0)      { x = col_hidden; w = w_cv_col; dst = cdcv; }
        else if (which == 1) { x = col_hidden; w = w_vc_col; dst = cdvc; }
        else                 { x = row_hidden; w = w_cv_row; dst = rdcv; }
        float v = x[row * 64 + lane] * w[lane];
        #pragma unroll
        for (int off = 32; off; off >>= 1) v += __shfl_down(v, off, 64);
        if (lane == 0) dst[row] = v;
        return;
    }
    if (blockIdx.x < 3088) {
        const int idx = (blockIdx.x - 3072) * 256 + t;   // 0..4095 f4 units
        if (idx < 2048) ((f4*)out_vo)[idx] = ((const f4*)vo_supp)[idx];
        else            ((f4*)out_co)[idx - 2048] = ((const f4*)co_supp)[idx - 2048];
        return;
    }
    attn_body(blockIdx.x - 3088, t, col_hidden, vo_supp, obj_hidden,
              w_attn_vo, b_attn_vo, voP, nullptr, nullptr, sA, sAcc);
}

// ---------------------------------------------------------------------------
// Standalone c->o attention (16 blocks), with fused rowdot_vc.
__global__ __launch_bounds__(256) void k_attn(
    const float* __restrict__ X, const float* __restrict__ supp,
    const float* __restrict__ obj, const float* __restrict__ wat,
    const float* __restrict__ bat, float* __restrict__ accP,
    const float* __restrict__ wextra, float* __restrict__ dextra)
{
    __shared__ float sA[256];
    __shared__ float sAcc[64];
    attn_body(blockIdx.x, threadIdx.x, X, supp, obj, wat, bat, accP,
              wextra, dextra, sA, sAcc);
}

// ---------------------------------------------------------------------------
// Big fused kernel: masked pairwise sigmoid scores + score @ B + supp passthrough.
//   out(i,h) = sum_j [supp0(i,j)!=0] sig(rdot[i]+cdot[j]+w0*supp0+w1*supp1+b) * B(j,h)
// ONE 64x64 tile per block (R3 lesson: the in-block tile loop ran the block in
// barrier lockstep, exposing full HBM latency every tile; R2 lesson: register
// prefetch across the loop spills). The pipeline now lives in the grid: 16
// queued blocks/CU — fresh blocks issue loads while older blocks run FMA.
// grid = 64 row-blocks * 64 j-splits + 1 = 4097.
__global__ __launch_bounds__(256, 4) void k_big(
    const float* __restrict__ supp0, const float* __restrict__ supp1,
    const float* __restrict__ Bm,
    const float* __restrict__ rdot, const float* __restrict__ cdot,
    const float* __restrict__ wsup, const float* __restrict__ bias,
    float* __restrict__ part, float* __restrict__ pass0, float* __restrict__ pass1,
    const float* __restrict__ objL, const float* __restrict__ objRp,
    const float* __restrict__ Wobj, float* __restrict__ objDst)
{
    __shared__ __align__(16) float sS[64][68];   // score tile, padded stride
    __shared__ __align__(16) float sB[64][64];   // B tile
    const int t = threadIdx.x;

    if (blockIdx.x == 4096) {
        // obj update: objDst[h] = relu([objL | sum_b objRp[b]] @ Wobj)
        float* rsum = &sS[0][0];
        if (t < 64) {
            float r = 0.f;
            for (int b = 0; b < 16; ++b) r += objRp[b*64 + t];
            rsum[t] = r;
        }
        __syncthreads();
        if (t < 64) {
            float acc = 0.f;
            for (int k = 0; k < 64; ++k) acc += objL[k] * Wobj[k*64 + t];
            for (int k = 0; k < 64; ++k) acc += rsum[k] * Wobj[(64+k)*64 + t];
            objDst[t] = fmaxf(acc, 0.f);
        }
        return;
    }

    const int bi = blockIdx.x & 63;
    const int bj = blockIdx.x >> 6;       // 0..63
    const int i0 = bi * 64;
    const int jt = bj * 64;
    const int jl4 = (t & 15) * 4;         // j/h offset within tile
    const int ilb = t >> 4;               // 0..15
    const float w0 = wsup[0], w1 = wsup[1], bv = bias[0];

    // stage B tile (contiguous 16 KB)
    {
        const f4* src = (const f4*)(Bm + (size_t)jt * 64);
        f4* dstp = (f4*)&sB[0][0];
        dstp[t]       = src[t];
        dstp[t + 256] = src[t + 256];
        dstp[t + 512] = src[t + 512];
        dstp[t + 768] = src[t + 768];
    }
    // score tile + fused nontemporal passthrough copy
    const f4 cd = *(const f4*)(cdot + jt + jl4);
    #pragma unroll
    for (int k = 0; k < 4; ++k) {
        const int il = ilb + 16 * k;
        const size_t idx = (size_t)(i0 + il) * 4096 + jt + jl4;
        f4 a0 = *(const f4*)(supp0 + idx);
        f4 a1 = *(const f4*)(supp1 + idx);
        __builtin_nontemporal_store(a0, (f4*)(pass0 + idx));
        __builtin_nontemporal_store(a1, (f4*)(pass1 + idx));
        const float rd = rdot[i0 + il];
        f4 lg = rd + cd + w0 * a0 + w1 * a1 + bv;
        f4 s;
        s.x = (a0.x != 0.f) ? sigf(lg.x) : 0.f;
        s.y = (a0.y != 0.f) ? sigf(lg.y) : 0.f;
        s.z = (a0.z != 0.f) ? sigf(lg.z) : 0.f;
        s.w = (a0.w != 0.f) ? sigf(lg.w) : 0.f;
        *(f4*)&sS[il][jl4] = s;
    }
    __syncthreads();
    // rank-64 update: 4 rows x 4 h per thread, all b128 LDS reads
    f4 acc0 = 0.f, acc1 = 0.f, acc2 = 0.f, acc3 = 0.f;
    const int h0 = jl4;
    #pragma unroll
    for (int jj = 0; jj < 64; jj += 4) {
        f4 b0 = *(const f4*)&sB[jj + 0][h0];
        f4 b1 = *(const f4*)&sB[jj + 1][h0];
        f4 b2 = *(const f4*)&sB[jj + 2][h0];
        f4 b3 = *(const f4*)&sB[jj + 3][h0];
        { f4 s = *(const f4*)&sS[ilb*4 + 0][jj]; acc0 += s.x*b0 + s.y*b1 + s.z*b2 + s.w*b3; }
        { f4 s = *(const f4*)&sS[ilb*4 + 1][jj]; acc1 += s.x*b0 + s.y*b1 + s.z*b2 + s.w*b3; }
        { f4 s = *(const f4*)&sS[ilb*4 + 2][jj]; acc2 += s.x*b0 + s.y*b1 + s.z*b2 + s.w*b3; }
        { f4 s = *(const f4*)&sS[ilb*4 + 3][jj]; acc3 += s.x*b0 + s.y*b1 + s.z*b2 + s.w*b3; }
    }
    // partials: regular stores (re-read next dispatch — let L2 keep them)
    float* pb = part + (size_t)bj * 262144 + (size_t)i0 * 64;
    *(f4*)(pb + (ilb*4 + 0)*64 + jl4) = acc0;
    *(f4*)(pb + (ilb*4 + 1)*64 + jl4) = acc1;
    *(f4*)(pb + (ilb*4 + 2)*64 + jl4) = acc2;
    *(f4*)(pb + (ilb*4 + 3)*64 + jl4) = acc3;
}

// ---------------------------------------------------------------------------
// Two-layer node update with fused 64-way partial reduction:
//   accin[n] = sum_j part[j][n]
//   mid = relu([objx | base[n]] @ W1);  dst[n] = relu([mid | accin[n]] @ W2)
// One wave per node row; grid = 1024 blocks x 256.
__global__ __launch_bounds__(256) void k_mlp2(
    const float* __restrict__ objx, const float* __restrict__ base,
    const float* __restrict__ W1, const float* __restrict__ part,
    const float* __restrict__ W2, float* __restrict__ dst)
{
    __shared__ float mid[4][64];
    __shared__ float accs[4][64];
    const int t = threadIdx.x, w = t >> 6, h = t & 63;
    const int n = blockIdx.x * 4 + w;
    float v = 0.f;
    #pragma unroll 8
    for (int j = 0; j < 64; ++j) v += part[(size_t)j * 262144 + n*64 + h];
    accs[w][h] = v;
    float m = 0.f;
    for (int k = 0; k < 64; ++k) m += objx[k] * W1[k*64 + h];
    for (int k = 0; k < 64; ++k) m += base[n*64 + k] * W1[(64+k)*64 + h];
    mid[w][h] = fmaxf(m, 0.f);
    __syncthreads();
    float o = 0.f;
    for (int k = 0; k < 64; ++k) o += mid[w][k] * W2[k*64 + h];
    for (int k = 0; k < 64; ++k) o += accs[w][k] * W2[(64+k)*64 + h];
    dst[n*64 + h] = fmaxf(o, 0.f);
}

extern "C" void kernel_launch(void* const* d_in, const int* in_sizes, int n_in,
                              void* d_out, int out_size, void* d_ws, size_t ws_size,
                              hipStream_t stream)
{
    const float* col_hidden = (const float*)d_in[0];
    const float* row_hidden = (const float*)d_in[1];
    const float* obj_hidden = (const float*)d_in[2];
    const float* cv_supp    = (const float*)d_in[3];
    const float* vc_supp    = (const float*)d_in[4];
    const float* vo_supp    = (const float*)d_in[5];
    const float* co_supp    = (const float*)d_in[6];
    const float* W_vo       = (const float*)d_in[7];
    const float* W_oc       = (const float*)d_in[8];
    const float* W_vc       = (const float*)d_in[9];
    const float* W_co       = (const float*)d_in[10];
    const float* W_ov       = (const float*)d_in[11];
    const float* W_cv       = (const float*)d_in[12];
    const float* w_attn_vo  = (const float*)d_in[13];
    const float* b_attn_vo  = (const float*)d_in[14];
    const float* w_attn_co  = (const float*)d_in[15];
    const float* b_attn_co  = (const float*)d_in[16];
    const float* w_cv_col   = (const float*)d_in[17];
    const float* w_cv_supp  = (const float*)d_in[18];
    const float* w_cv_row   = (const float*)d_in[19];
    const float* b_cv       = (const float*)d_in[20];
    const float* w_vc_row   = (const float*)d_in[21];
    const float* w_vc_supp  = (const float*)d_in[22];
    const float* w_vc_col   = (const float*)d_in[23];
    const float* b_vc       = (const float*)d_in[24];

    float* out = (float*)d_out;
    float* ws  = (float*)d_ws;

    // 1) dots + small passthrough + v->o attention partials
    k_front<<<3104, 256, 0, stream>>>(col_hidden, row_hidden, w_cv_col, w_vc_col, w_cv_row,
                                      ws + WS_CDCV, ws + WS_CDVC, ws + WS_RDCV,
                                      vo_supp, co_supp, out + OUT_VO, out + OUT_CO,
                                      obj_hidden, w_attn_vo, b_attn_vo, ws + WS_VO_P);
    // 2) v->c big masked matmul (+ fused cv_supp passthrough, + obj v->o update)
    k_big<<<4097, 256, 0, stream>>>(cv_supp, cv_supp + PLANE, col_hidden,
                                    ws + WS_RDCV, ws + WS_CDCV, w_cv_supp, b_cv,
                                    ws + WS_PART, out + OUT_CV, out + OUT_CV + PLANE,
                                    obj_hidden, ws + WS_VO_P, W_vo, ws + WS_OBJ1);
    // 3) row_next = relu([relu([obj1|row_hidden]W_oc) | v_out] W_vc)
    k_mlp2<<<1024, 256, 0, stream>>>(ws + WS_OBJ1, row_hidden, W_oc, ws + WS_PART, W_vc,
                                     out + OUT_ROW);
    // 4) c->o attention partials (+ fused rowdot_vc over row_next)
    k_attn<<<16, 256, 0, stream>>>(out + OUT_ROW, co_supp, ws + WS_OBJ1, w_attn_co, b_attn_co,
                                   ws + WS_CO_P, w_vc_row, ws + WS_RDVC);
    // 5) c->v big masked matmul (+ fused vc_supp passthrough, + obj c->o update)
    k_big<<<4097, 256, 0, stream>>>(vc_supp, vc_supp + PLANE, out + OUT_ROW,
                                    ws + WS_CDVC, ws + WS_RDVC, w_vc_supp, b_vc,
                                    ws + WS_PART, out + OUT_VC, out + OUT_VC + PLANE,
                                    ws + WS_OBJ1, ws + WS_CO_P, W_co, out + OUT_OBJ);
    // 6) col_next = relu([relu([obj|col_hidden]W_ov) | c_out] W_cv)
    k_mlp2<<<1024, 256, 0, stream>>>(out + OUT_OBJ, col_hidden, W_ov, ws + WS_PART, W_cv,
                                     out + OUT_COL);
}

// Round 5
// 564.139 us; speedup vs baseline: 1.0423x; 1.0423x over previous
//
#include <hip/hip_runtime.h>
#include <math.h>

typedef float f4 __attribute__((ext_vector_type(4)));

#define PLANE (4096*4096)

// ---- output offsets (floats), concatenated return order ----
#define OUT_COL 0
#define OUT_ROW 262144
#define OUT_OBJ 524288
#define OUT_CV  524352
#define OUT_VC  34078784
#define OUT_VO  67633216
#define OUT_CO  67641408

// ---- workspace offsets (floats) ----
#define WS_VO_P 0        // [16][64] v->o attention per-block partials
#define WS_CO_P 1024     // [16][64] c->o attention per-block partials
#define WS_OBJ1 2048     // [64]  obj after v->o update
#define WS_RDCV 2112     // [4096] row_hidden . w_cv_row
#define WS_CDCV 6208     // [4096] col_hidden . w_cv_col
#define WS_RDVC 10304    // [4096] row_next . w_vc_row
#define WS_CDVC 14400    // [4096] col_hidden . w_vc_col
#define WS_PART 18496    // [64][4096*64] j-split partials (64 MB)

__device__ __forceinline__ float sigf(float x) {
    return 1.0f / (1.0f + __expf(-x));
}

// ---------------------------------------------------------------------------
// Attention body over 4096 nodes (one 256-thread block handles 256 nodes):
//   a[i] = sigmoid(X[i].wat[0:64] + supp[i].wat[64:66] + obj.wat[66:130] + b)
//   accP[blk][h] = sum_{i in blk} a[i]*X[i,h]   (per-block partial, no atomics)
// Optionally dextra[i] = X[i].wextra (fused row_next . w_vc_row).
__device__ __forceinline__ void attn_body(
    int blk, int t, const float* __restrict__ X, const float* __restrict__ supp,
    const float* __restrict__ obj, const float* __restrict__ wat,
    const float* __restrict__ bat, float* __restrict__ accP,
    const float* __restrict__ wextra, float* __restrict__ dextra,
    float* sA, float* sAcc)
{
    const int i = blk * 256 + t;
    float od = 0.f;
    for (int h = 0; h < 64; ++h) od += obj[h] * wat[66 + h];
    float x = bat[0] + od + supp[i*2] * wat[64] + supp[i*2+1] * wat[65];
    const f4* Xr = (const f4*)(X + i*64);
    f4 xd = 0.f, dd = 0.f;
    #pragma unroll
    for (int q = 0; q < 16; ++q) {
        f4 xv = Xr[q];
        xd += xv * ((const f4*)wat)[q];
        if (wextra) dd += xv * ((const f4*)wextra)[q];
    }
    x += xd.x + xd.y + xd.z + xd.w;
    if (dextra) dextra[i] = dd.x + dd.y + dd.z + dd.w;
    sA[t] = sigf(x);
    if (t < 64) sAcc[t] = 0.f;
    __syncthreads();
    const int w = t >> 6, h = t & 63;
    const int base = blk * 256 + w * 64;
    float partial = 0.f;
    for (int j = 0; j < 64; ++j)
        partial += sA[w*64 + j] * X[(base + j)*64 + h];
    atomicAdd(&sAcc[h], partial);
    __syncthreads();
    if (t < 64) accP[blk*64 + t] = sAcc[t];
}

// ---------------------------------------------------------------------------
// Front kernel: 3072 dot blocks + 16 small-copy blocks + 16 v->o attention blocks.
__global__ __launch_bounds__(256) void k_front(
    const float* __restrict__ col_hidden, const float* __restrict__ row_hidden,
    const float* __restrict__ w_cv_col, const float* __restrict__ w_vc_col,
    const float* __restrict__ w_cv_row,
    float* __restrict__ cdcv, float* __restrict__ cdvc, float* __restrict__ rdcv,
    const float* __restrict__ vo_supp, const float* __restrict__ co_supp,
    float* __restrict__ out_vo, float* __restrict__ out_co,
    const float* __restrict__ obj_hidden, const float* __restrict__ w_attn_vo,
    const float* __restrict__ b_attn_vo, float* __restrict__ voP)
{
    __shared__ float sA[256];
    __shared__ float sAcc[64];
    const int t = threadIdx.x;
    if (blockIdx.x < 3072) {
        const int gw = blockIdx.x * 4 + (t >> 6);
        const int lane = t & 63;
        const int which = gw >> 12;       // 0,1,2
        const int row = gw & 4095;
        const float* x; const float* w; float* dst;
        if (which == 0)      { x = col_hidden; w = w_cv_col; dst = cdcv; }
        else if (which == 1) { x = col_hidden; w = w_vc_col; dst = cdvc; }
        else                 { x = row_hidden; w = w_cv_row; dst = rdcv; }
        float v = x[row * 64 + lane] * w[lane];
        #pragma unroll
        for (int off = 32; off; off >>= 1) v += __shfl_down(v, off, 64);
        if (lane == 0) dst[row] = v;
        return;
    }
    if (blockIdx.x < 3088) {
        const int idx = (blockIdx.x - 3072) * 256 + t;   // 0..4095 f4 units
        if (idx < 2048) ((f4*)out_vo)[idx] = ((const f4*)vo_supp)[idx];
        else            ((f4*)out_co)[idx - 2048] = ((const f4*)co_supp)[idx - 2048];
        return;
    }
    attn_body(blockIdx.x - 3088, t, col_hidden, vo_supp, obj_hidden,
              w_attn_vo, b_attn_vo, voP, nullptr, nullptr, sA, sAcc);
}

// ---------------------------------------------------------------------------
// Standalone c->o attention (16 blocks), with fused rowdot_vc.
__global__ __launch_bounds__(256) void k_attn(
    const float* __restrict__ X, const float* __restrict__ supp,
    const float* __restrict__ obj, const float* __restrict__ wat,
    const float* __restrict__ bat, float* __restrict__ accP,
    const float* __restrict__ wextra, float* __restrict__ dextra)
{
    __shared__ float sA[256];
    __shared__ float sAcc[64];
    attn_body(blockIdx.x, threadIdx.x, X, supp, obj, wat, bat, accP,
              wextra, dextra, sA, sAcc);
}

// ---------------------------------------------------------------------------
// Big fused kernel: masked pairwise sigmoid scores + score @ B + supp passthrough.
//   out(i,h) = sum_j [supp0(i,j)!=0] sig(rdot[i]+cdot[j]+w0*supp0+w1*supp1+b) * B(j,h)
// One 64x64 tile per block. R4 lesson: dur is invariant to wave scheduling
// (in-block loops vs grid pipeline all ~150us @ 2.2 TB/s) -> the limiter is
// the DRAM address stream. With bi fast-varying, co-resident blocks touched a
// ~4KB j-window at 16KB row stride (channel camping). DECODE SWAPPED: bj is
// now the fast index, so 64 consecutive blocks sweep one 64-row band's full
// 16KB row extent -> contiguous MB-scale bands active per instant.
// grid = 64 row-blocks * 64 j-splits + 1 = 4097.
__global__ __launch_bounds__(256, 4) void k_big(
    const float* __restrict__ supp0, const float* __restrict__ supp1,
    const float* __restrict__ Bm,
    const float* __restrict__ rdot, const float* __restrict__ cdot,
    const float* __restrict__ wsup, const float* __restrict__ bias,
    float* __restrict__ part, float* __restrict__ pass0, float* __restrict__ pass1,
    const float* __restrict__ objL, const float* __restrict__ objRp,
    const float* __restrict__ Wobj, float* __restrict__ objDst)
{
    __shared__ __align__(16) float sS[64][68];   // score tile, padded stride
    __shared__ __align__(16) float sB[64][64];   // B tile
    const int t = threadIdx.x;

    if (blockIdx.x == 4096) {
        // obj update: objDst[h] = relu([objL | sum_b objRp[b]] @ Wobj)
        float* rsum = &sS[0][0];
        if (t < 64) {
            float r = 0.f;
            for (int b = 0; b < 16; ++b) r += objRp[b*64 + t];
            rsum[t] = r;
        }
        __syncthreads();
        if (t < 64) {
            float acc = 0.f;
            for (int k = 0; k < 64; ++k) acc += objL[k] * Wobj[k*64 + t];
            for (int k = 0; k < 64; ++k) acc += rsum[k] * Wobj[(64+k)*64 + t];
            objDst[t] = fmaxf(acc, 0.f);
        }
        return;
    }

    const int bi = blockIdx.x >> 6;       // SLOW index: row-block 0..63
    const int bj = blockIdx.x & 63;       // FAST index: j-split 0..63
    const int i0 = bi * 64;
    const int jt = bj * 64;
    const int jl4 = (t & 15) * 4;         // j/h offset within tile
    const int ilb = t >> 4;               // 0..15
    const float w0 = wsup[0], w1 = wsup[1], bv = bias[0];

    // stage B tile (contiguous 16 KB)
    {
        const f4* src = (const f4*)(Bm + (size_t)jt * 64);
        f4* dstp = (f4*)&sB[0][0];
        dstp[t]       = src[t];
        dstp[t + 256] = src[t + 256];
        dstp[t + 512] = src[t + 512];
        dstp[t + 768] = src[t + 768];
    }
    // score tile + fused nontemporal passthrough copy
    const f4 cd = *(const f4*)(cdot + jt + jl4);
    #pragma unroll
    for (int k = 0; k < 4; ++k) {
        const int il = ilb + 16 * k;
        const size_t idx = (size_t)(i0 + il) * 4096 + jt + jl4;
        f4 a0 = *(const f4*)(supp0 + idx);
        f4 a1 = *(const f4*)(supp1 + idx);
        __builtin_nontemporal_store(a0, (f4*)(pass0 + idx));
        __builtin_nontemporal_store(a1, (f4*)(pass1 + idx));
        const float rd = rdot[i0 + il];
        f4 lg = rd + cd + w0 * a0 + w1 * a1 + bv;
        f4 s;
        s.x = (a0.x != 0.f) ? sigf(lg.x) : 0.f;
        s.y = (a0.y != 0.f) ? sigf(lg.y) : 0.f;
        s.z = (a0.z != 0.f) ? sigf(lg.z) : 0.f;
        s.w = (a0.w != 0.f) ? sigf(lg.w) : 0.f;
        *(f4*)&sS[il][jl4] = s;
    }
    __syncthreads();
    // rank-64 update: 4 rows x 4 h per thread, all b128 LDS reads
    f4 acc0 = 0.f, acc1 = 0.f, acc2 = 0.f, acc3 = 0.f;
    const int h0 = jl4;
    #pragma unroll
    for (int jj = 0; jj < 64; jj += 4) {
        f4 b0 = *(const f4*)&sB[jj + 0][h0];
        f4 b1 = *(const f4*)&sB[jj + 1][h0];
        f4 b2 = *(const f4*)&sB[jj + 2][h0];
        f4 b3 = *(const f4*)&sB[jj + 3][h0];
        { f4 s = *(const f4*)&sS[ilb*4 + 0][jj]; acc0 += s.x*b0 + s.y*b1 + s.z*b2 + s.w*b3; }
        { f4 s = *(const f4*)&sS[ilb*4 + 1][jj]; acc1 += s.x*b0 + s.y*b1 + s.z*b2 + s.w*b3; }
        { f4 s = *(const f4*)&sS[ilb*4 + 2][jj]; acc2 += s.x*b0 + s.y*b1 + s.z*b2 + s.w*b3; }
        { f4 s = *(const f4*)&sS[ilb*4 + 3][jj]; acc3 += s.x*b0 + s.y*b1 + s.z*b2 + s.w*b3; }
    }
    // partials: regular stores (re-read next dispatch — let L2 keep them)
    float* pb = part + (size_t)bj * 262144 + (size_t)i0 * 64;
    *(f4*)(pb + (ilb*4 + 0)*64 + jl4) = acc0;
    *(f4*)(pb + (ilb*4 + 1)*64 + jl4) = acc1;
    *(f4*)(pb + (ilb*4 + 2)*64 + jl4) = acc2;
    *(f4*)(pb + (ilb*4 + 3)*64 + jl4) = acc3;
}

// ---------------------------------------------------------------------------
// Two-layer node update with fused 64-way partial reduction:
//   accin[n] = sum_j part[j][n]
//   mid = relu([objx | base[n]] @ W1);  dst[n] = relu([mid | accin[n]] @ W2)
// One wave per node row; grid = 1024 blocks x 256.
__global__ __launch_bounds__(256) void k_mlp2(
    const float* __restrict__ objx, const float* __restrict__ base,
    const float* __restrict__ W1, const float* __restrict__ part,
    const float* __restrict__ W2, float* __restrict__ dst)
{
    __shared__ float mid[4][64];
    __shared__ float accs[4][64];
    const int t = threadIdx.x, w = t >> 6, h = t & 63;
    const int n = blockIdx.x * 4 + w;
    float v = 0.f;
    #pragma unroll 8
    for (int j = 0; j < 64; ++j) v += part[(size_t)j * 262144 + n*64 + h];
    accs[w][h] = v;
    float m = 0.f;
    for (int k = 0; k < 64; ++k) m += objx[k] * W1[k*64 + h];
    for (int k = 0; k < 64; ++k) m += base[n*64 + k] * W1[(64+k)*64 + h];
    mid[w][h] = fmaxf(m, 0.f);
    __syncthreads();
    float o = 0.f;
    for (int k = 0; k < 64; ++k) o += mid[w][k] * W2[k*64 + h];
    for (int k = 0; k < 64; ++k) o += accs[w][k] * W2[(64+k)*64 + h];
    dst[n*64 + h] = fmaxf(o, 0.f);
}

extern "C" void kernel_launch(void* const* d_in, const int* in_sizes, int n_in,
                              void* d_out, int out_size, void* d_ws, size_t ws_size,
                              hipStream_t stream)
{
    const float* col_hidden = (const float*)d_in[0];
    const float* row_hidden = (const float*)d_in[1];
    const float* obj_hidden = (const float*)d_in[2];
    const float* cv_supp    = (const float*)d_in[3];
    const float* vc_supp    = (const float*)d_in[4];
    const float* vo_supp    = (const float*)d_in[5];
    const float* co_supp    = (const float*)d_in[6];
    const float* W_vo       = (const float*)d_in[7];
    const float* W_oc       = (const float*)d_in[8];
    const float* W_vc       = (const float*)d_in[9];
    const float* W_co       = (const float*)d_in[10];
    const float* W_ov       = (const float*)d_in[11];
    const float* W_cv       = (const float*)d_in[12];
    const float* w_attn_vo  = (const float*)d_in[13];
    const float* b_attn_vo  = (const float*)d_in[14];
    const float* w_attn_co  = (const float*)d_in[15];
    const float* b_attn_co  = (const float*)d_in[16];
    const float* w_cv_col   = (const float*)d_in[17];
    const float* w_cv_supp  = (const float*)d_in[18];
    const float* w_cv_row   = (const float*)d_in[19];
    const float* b_cv       = (const float*)d_in[20];
    const float* w_vc_row   = (const float*)d_in[21];
    const float* w_vc_supp  = (const float*)d_in[22];
    const float* w_vc_col   = (const float*)d_in[23];
    const float* b_vc       = (const float*)d_in[24];

    float* out = (float*)d_out;
    float* ws  = (float*)d_ws;

    // 1) dots + small passthrough + v->o attention partials
    k_front<<<3104, 256, 0, stream>>>(col_hidden, row_hidden, w_cv_col, w_vc_col, w_cv_row,
                                      ws + WS_CDCV, ws + WS_CDVC, ws + WS_RDCV,
                                      vo_supp, co_supp, out + OUT_VO, out + OUT_CO,
                                      obj_hidden, w_attn_vo, b_attn_vo, ws + WS_VO_P);
    // 2) v->c big masked matmul (+ fused cv_supp passthrough, + obj v->o update)
    k_big<<<4097, 256, 0, stream>>>(cv_supp, cv_supp + PLANE, col_hidden,
                                    ws + WS_RDCV, ws + WS_CDCV, w_cv_supp, b_cv,
                                    ws + WS_PART, out + OUT_CV, out + OUT_CV + PLANE,
                                    obj_hidden, ws + WS_VO_P, W_vo, ws + WS_OBJ1);
    // 3) row_next = relu([relu([obj1|row_hidden]W_oc) | v_out] W_vc)
    k_mlp2<<<1024, 256, 0, stream>>>(ws + WS_OBJ1, row_hidden, W_oc, ws + WS_PART, W_vc,
                                     out + OUT_ROW);
    // 4) c->o attention partials (+ fused rowdot_vc over row_next)
    k_attn<<<16, 256, 0, stream>>>(out + OUT_ROW, co_supp, ws + WS_OBJ1, w_attn_co, b_attn_co,
                                   ws + WS_CO_P, w_vc_row, ws + WS_RDVC);
    // 5) c->v big masked matmul (+ fused vc_supp passthrough, + obj c->o update)
    k_big<<<4097, 256, 0, stream>>>(vc_supp, vc_supp + PLANE, out + OUT_ROW,
                                    ws + WS_CDVC, ws + WS_RDVC, w_vc_supp, b_vc,
                                    ws + WS_PART, out + OUT_VC, out + OUT_VC + PLANE,
                                    ws + WS_OBJ1, ws + WS_CO_P, W_co, out + OUT_OBJ);
    // 6) col_next = relu([relu([obj|col_hidden]W_ov) | c_out] W_cv)
    k_mlp2<<<1024, 256, 0, stream>>>(out + OUT_OBJ, col_hidden, W_ov, ws + WS_PART, W_cv,
                                     out + OUT_COL);
}